// Round 1
// baseline (358.010 us; speedup 1.0000x reference)
//
#include <hip/hip_runtime.h>

typedef _Float16 f16;
typedef _Float16 half8 __attribute__((ext_vector_type(8)));
typedef float f32x4 __attribute__((ext_vector_type(4)));
typedef float float4v __attribute__((ext_vector_type(4)));

#define LOG2E 1.44269504088896340736f

// Problem constants
// B=2, S=4096, d_model=512, H=8, d_k=64, M = B*S = 8192

// ---------------------------------------------------------------------------
// QKV projection: C_z[i][j] = sum_d A_z[i][d] * W_z[j][d] + b_z[j]
// A: fp32 (8192 x 512), W: fp32 (512 x 512) row-major (used as W^T in GEMM).
// Output: fp16, layout (b, h, s, dd)  [dst[((b*8+h)*4096+s)*64+dd]]
// Tile: BM=128, BN=128, BK=32; 4 waves; wave owns 64x64 (4x4 MFMA frags).
// ---------------------------------------------------------------------------
__global__ __launch_bounds__(256) void qkv_proj(
    const float* __restrict__ Aq, const float* __restrict__ Ak, const float* __restrict__ Av,
    const float* __restrict__ Wq, const float* __restrict__ Wk, const float* __restrict__ Wv,
    const float* __restrict__ bq, const float* __restrict__ bk, const float* __restrict__ bv,
    f16* __restrict__ Qh, f16* __restrict__ Kh, f16* __restrict__ Vh)
{
    const int z = blockIdx.z;
    const float* __restrict__ A    = (z == 0) ? Aq : (z == 1) ? Ak : Av;
    const float* __restrict__ W    = (z == 0) ? Wq : (z == 1) ? Wk : Wv;
    const float* __restrict__ bias = (z == 0) ? bq : (z == 1) ? bk : bv;
    f16* __restrict__ dst          = (z == 0) ? Qh : (z == 1) ? Kh : Vh;

    // stride 40 fp16 (80 B) -> 2-way bank conflicts max on b128 reads
    __shared__ __align__(16) f16 As[128 * 40];
    __shared__ __align__(16) f16 Ws[128 * 40];

    const int t  = threadIdx.x;
    const int m0 = blockIdx.y * 128;
    const int n0 = blockIdx.x * 128;
    const int w = t >> 6, lane = t & 63, lr = lane & 15, lg = lane >> 4;
    const int wr = w >> 1, wc = w & 1;

    f32x4 acc[4][4] = {};

    for (int k0 = 0; k0 < 512; k0 += 32) {
        // ---- stage A tile (128x32) and W tile (128x32), fp32 -> fp16 ----
        #pragma unroll
        for (int it = 0; it < 2; ++it) {
            int c = t + it * 256;                 // 0..511
            int row  = c >> 2;                    // 0..127
            int col8 = (c & 3) * 8;               // 0,8,16,24

            const float* ga = A + (size_t)(m0 + row) * 512 + k0 + col8;
            float4v a0 = *(const float4v*)ga;
            float4v a1 = *(const float4v*)(ga + 4);
            half8 ha;
            ha[0] = (f16)a0[0]; ha[1] = (f16)a0[1]; ha[2] = (f16)a0[2]; ha[3] = (f16)a0[3];
            ha[4] = (f16)a1[0]; ha[5] = (f16)a1[1]; ha[6] = (f16)a1[2]; ha[7] = (f16)a1[3];
            *(half8*)&As[row * 40 + col8] = ha;

            const float* gw = W + (size_t)(n0 + row) * 512 + k0 + col8;
            float4v w0 = *(const float4v*)gw;
            float4v w1 = *(const float4v*)(gw + 4);
            half8 hw;
            hw[0] = (f16)w0[0]; hw[1] = (f16)w0[1]; hw[2] = (f16)w0[2]; hw[3] = (f16)w0[3];
            hw[4] = (f16)w1[0]; hw[5] = (f16)w1[1]; hw[6] = (f16)w1[2]; hw[7] = (f16)w1[3];
            *(half8*)&Ws[row * 40 + col8] = hw;
        }
        __syncthreads();

        // ---- MFMA: wave quadrant 64x64, one K=32 step ----
        half8 af[4], bf[4];
        #pragma unroll
        for (int i = 0; i < 4; ++i) {
            af[i] = *(const half8*)&As[(wr * 64 + i * 16 + lr) * 40 + lg * 8];
            bf[i] = *(const half8*)&Ws[(wc * 64 + i * 16 + lr) * 40 + lg * 8];
        }
        #pragma unroll
        for (int mi = 0; mi < 4; ++mi)
            #pragma unroll
            for (int ni = 0; ni < 4; ++ni)
                acc[mi][ni] = __builtin_amdgcn_mfma_f32_16x16x32_f16(af[mi], bf[ni], acc[mi][ni], 0, 0, 0);
        __syncthreads();
    }

    // ---- epilogue: bias add, remap to (b,h,s,dd), fp16 store ----
    #pragma unroll
    for (int mi = 0; mi < 4; ++mi) {
        #pragma unroll
        for (int ni = 0; ni < 4; ++ni) {
            int col = n0 + wc * 64 + ni * 16 + lr;     // 0..511
            float bv_ = bias[col];
            int h  = col >> 6;
            int dd = col & 63;
            #pragma unroll
            for (int r = 0; r < 4; ++r) {
                int row = m0 + wr * 64 + mi * 16 + lg * 4 + r;  // 0..8191
                int b = row >> 12;
                int s = row & 4095;
                dst[(((size_t)(b * 8 + h)) * 4096 + s) * 64 + dd] = (f16)(acc[mi][ni][r] + bv_);
            }
        }
    }
}

// ---------------------------------------------------------------------------
// Flash attention (no mask), per (b,h). Q,K,V fp16 in (b,h,s,dd).
// softmax WITHOUT pre-scale; division by sqrt(d_k)=8 folded into epilogue.
// Output X fp16 in (b, s, h, dd) == row-major (8192 x 512).
// Block: 256 thr (4 waves). BQ=128 (32 q-rows/wave), BK=64 keys/tile.
// ---------------------------------------------------------------------------
__global__ __launch_bounds__(256) void flash_attn(
    const f16* __restrict__ Qh, const f16* __restrict__ Kh, const f16* __restrict__ Vh,
    f16* __restrict__ Xh)
{
    const int bh  = blockIdx.y;           // 0..15  (b*8 + h)
    const int q0b = blockIdx.x * 128;
    const int t = threadIdx.x, w = t >> 6, lane = t & 63, lr = lane & 15, lg = lane >> 4;
    const int q0 = q0b + w * 32;

    __shared__ __align__(16) f16 Ks[64 * 72];       // K tile, row-major [kpos][d], stride 72
    __shared__ __align__(16) f16 Vt[64 * 72];       // V tile transposed [dd][kpos], stride 72
    __shared__ __align__(16) f16 Ps[4 * 32 * 72];   // per-wave P [qrow][kpos], stride 72
    f16* Pw = &Ps[w * 32 * 72];

    const size_t hb = (size_t)bh * 4096 * 64;

    // Q fragments in registers: A[m=qrow][k=d], rows q0..q0+31, d=0..63
    half8 aq[2][2];
    #pragma unroll
    for (int mi = 0; mi < 2; ++mi)
        #pragma unroll
        for (int c = 0; c < 2; ++c)
            aq[mi][c] = *(const half8*)&Qh[hb + (size_t)(q0 + mi * 16 + lr) * 64 + c * 32 + lg * 8];

    f32x4 o[2][4] = {};
    float mrun[2][4], lrun[2][4];
    #pragma unroll
    for (int mi = 0; mi < 2; ++mi)
        #pragma unroll
        for (int r = 0; r < 4; ++r) { mrun[mi][r] = -INFINITY; lrun[mi][r] = 0.0f; }

    for (int kt = 0; kt < 4096; kt += 64) {
        // ---- stage K (row-major) and V (transposed) ----
        #pragma unroll
        for (int it = 0; it < 2; ++it) {
            int c = t + it * 256;                  // 0..511
            int row  = c >> 3;                     // 0..63
            int col8 = (c & 7) * 8;                // 0..56
            *(half8*)&Ks[row * 72 + col8] =
                *(const half8*)&Kh[hb + (size_t)(kt + row) * 64 + col8];

            int kp  = c & 63;
            int dd8 = (c >> 6) * 8;
            half8 v8 = *(const half8*)&Vh[hb + (size_t)(kt + kp) * 64 + dd8];
            #pragma unroll
            for (int j = 0; j < 8; ++j)
                Vt[(dd8 + j) * 72 + kp] = v8[j];
        }
        __syncthreads();

        // ---- S = Q K^T  (M=32 q-rows, N=64 keys, K=64 d) ----
        f32x4 sf[2][4] = {};
        #pragma unroll
        for (int c = 0; c < 2; ++c) {
            half8 bk_[4];
            #pragma unroll
            for (int ni = 0; ni < 4; ++ni)
                bk_[ni] = *(const half8*)&Ks[(ni * 16 + lr) * 72 + c * 32 + lg * 8];
            #pragma unroll
            for (int mi = 0; mi < 2; ++mi)
                #pragma unroll
                for (int ni = 0; ni < 4; ++ni)
                    sf[mi][ni] = __builtin_amdgcn_mfma_f32_16x16x32_f16(aq[mi][c], bk_[ni], sf[mi][ni], 0, 0, 0);
        }

        // ---- online softmax (row = mi*16 + lg*4 + r, cols spread over 16 lanes x 4 frags)
        #pragma unroll
        for (int mi = 0; mi < 2; ++mi) {
            #pragma unroll
            for (int r = 0; r < 4; ++r) {
                float vmax = fmaxf(fmaxf(sf[mi][0][r], sf[mi][1][r]),
                                   fmaxf(sf[mi][2][r], sf[mi][3][r]));
                #pragma unroll
                for (int m = 1; m < 16; m <<= 1)
                    vmax = fmaxf(vmax, __shfl_xor(vmax, m, 64));
                float mnew  = fmaxf(mrun[mi][r], vmax);
                float alpha = __builtin_amdgcn_exp2f((mrun[mi][r] - mnew) * LOG2E);
                float rs = 0.0f;
                #pragma unroll
                for (int ni = 0; ni < 4; ++ni) {
                    float p = __builtin_amdgcn_exp2f((sf[mi][ni][r] - mnew) * LOG2E);
                    sf[mi][ni][r] = p;
                    rs += p;
                }
                #pragma unroll
                for (int m = 1; m < 16; m <<= 1)
                    rs += __shfl_xor(rs, m, 64);
                lrun[mi][r] = lrun[mi][r] * alpha + rs;
                mrun[mi][r] = mnew;
                #pragma unroll
                for (int ni = 0; ni < 4; ++ni)
                    o[mi][ni][r] *= alpha;
            }
        }

        // ---- write P to LDS fp16 (D-layout -> memory), then read as A-frags
        #pragma unroll
        for (int mi = 0; mi < 2; ++mi)
            #pragma unroll
            for (int ni = 0; ni < 4; ++ni)
                #pragma unroll
                for (int r = 0; r < 4; ++r)
                    Pw[(mi * 16 + lg * 4 + r) * 72 + ni * 16 + lr] = (f16)sf[mi][ni][r];
        __syncthreads();

        // ---- O += P @ V   (K-dim = 64 keys, N = 64 dd) ----
        #pragma unroll
        for (int c = 0; c < 2; ++c) {
            half8 ap[2], bv_[4];
            #pragma unroll
            for (int mi = 0; mi < 2; ++mi)
                ap[mi] = *(const half8*)&Pw[(mi * 16 + lr) * 72 + c * 32 + lg * 8];
            #pragma unroll
            for (int ni = 0; ni < 4; ++ni)
                bv_[ni] = *(const half8*)&Vt[(ni * 16 + lr) * 72 + c * 32 + lg * 8];
            #pragma unroll
            for (int mi = 0; mi < 2; ++mi)
                #pragma unroll
                for (int ni = 0; ni < 4; ++ni)
                    o[mi][ni] = __builtin_amdgcn_mfma_f32_16x16x32_f16(ap[mi], bv_[ni], o[mi][ni], 0, 0, 0);
        }
        __syncthreads();
    }

    // ---- epilogue: O / (l * 8), write (b, s, h, dd) fp16 ----
    const int b = bh >> 3, h = bh & 7;
    #pragma unroll
    for (int mi = 0; mi < 2; ++mi) {
        #pragma unroll
        for (int r = 0; r < 4; ++r) {
            float inv = 1.0f / (lrun[mi][r] * 8.0f);
            int q = q0 + mi * 16 + lg * 4 + r;
            #pragma unroll
            for (int ni = 0; ni < 4; ++ni) {
                int dd = ni * 16 + lr;
                Xh[((size_t)(b * 4096 + q)) * 512 + h * 64 + dd] = (f16)(o[mi][ni][r] * inv);
            }
        }
    }
}

// ---------------------------------------------------------------------------
// Output projection: out[i][j] = sum_d X[i][d] * Wo[j][d] + bo[j], fp32 out.
// X: fp16 (8192 x 512) row-major. Same tile structure as qkv_proj.
// ---------------------------------------------------------------------------
__global__ __launch_bounds__(256) void out_proj(
    const f16* __restrict__ Xh, const float* __restrict__ Wo, const float* __restrict__ bo,
    float* __restrict__ out)
{
    __shared__ __align__(16) f16 As[128 * 40];
    __shared__ __align__(16) f16 Ws[128 * 40];

    const int t  = threadIdx.x;
    const int m0 = blockIdx.y * 128;
    const int n0 = blockIdx.x * 128;
    const int w = t >> 6, lane = t & 63, lr = lane & 15, lg = lane >> 4;
    const int wr = w >> 1, wc = w & 1;

    f32x4 acc[4][4] = {};

    for (int k0 = 0; k0 < 512; k0 += 32) {
        #pragma unroll
        for (int it = 0; it < 2; ++it) {
            int c = t + it * 256;
            int row  = c >> 2;
            int col8 = (c & 3) * 8;

            *(half8*)&As[row * 40 + col8] =
                *(const half8*)&Xh[(size_t)(m0 + row) * 512 + k0 + col8];

            const float* gw = Wo + (size_t)(n0 + row) * 512 + k0 + col8;
            float4v w0 = *(const float4v*)gw;
            float4v w1 = *(const float4v*)(gw + 4);
            half8 hw;
            hw[0] = (f16)w0[0]; hw[1] = (f16)w0[1]; hw[2] = (f16)w0[2]; hw[3] = (f16)w0[3];
            hw[4] = (f16)w1[0]; hw[5] = (f16)w1[1]; hw[6] = (f16)w1[2]; hw[7] = (f16)w1[3];
            *(half8*)&Ws[row * 40 + col8] = hw;
        }
        __syncthreads();

        half8 af[4], bf[4];
        #pragma unroll
        for (int i = 0; i < 4; ++i) {
            af[i] = *(const half8*)&As[(wr * 64 + i * 16 + lr) * 40 + lg * 8];
            bf[i] = *(const half8*)&Ws[(wc * 64 + i * 16 + lr) * 40 + lg * 8];
        }
        #pragma unroll
        for (int mi = 0; mi < 4; ++mi)
            #pragma unroll
            for (int ni = 0; ni < 4; ++ni)
                acc[mi][ni] = __builtin_amdgcn_mfma_f32_16x16x32_f16(af[mi], bf[ni], acc[mi][ni], 0, 0, 0);
        __syncthreads();
    }

    #pragma unroll
    for (int mi = 0; mi < 4; ++mi) {
        #pragma unroll
        for (int ni = 0; ni < 4; ++ni) {
            int col = n0 + wc * 64 + ni * 16 + lr;
            float bb = bo[col];
            #pragma unroll
            for (int r = 0; r < 4; ++r) {
                int row = m0 + wr * 64 + mi * 16 + lg * 4 + r;
                out[(size_t)row * 512 + col] = acc[mi][ni][r] + bb;
            }
        }
    }
}

// ---------------------------------------------------------------------------
extern "C" void kernel_launch(void* const* d_in, const int* in_sizes, int n_in,
                              void* d_out, int out_size, void* d_ws, size_t ws_size,
                              hipStream_t stream) {
    const float* query = (const float*)d_in[0];
    const float* key   = (const float*)d_in[1];
    const float* value = (const float*)d_in[2];
    const float* Wq    = (const float*)d_in[3];
    const float* bq    = (const float*)d_in[4];
    const float* Wk    = (const float*)d_in[5];
    const float* bk    = (const float*)d_in[6];
    const float* Wv    = (const float*)d_in[7];
    const float* bv    = (const float*)d_in[8];
    const float* Wo    = (const float*)d_in[9];
    const float* bo    = (const float*)d_in[10];
    float* out = (float*)d_out;

    char* ws = (char*)d_ws;
    f16* Qh = (f16*)(ws);                    // 2*8*4096*64 fp16 = 8 MiB
    f16* Kh = (f16*)(ws + 8388608);
    f16* Vh = (f16*)(ws + 16777216);
    f16* Xh = (f16*)(ws + 25165824);         // attention output, 8 MiB

    // 1) Q/K/V projections (fp32 -> fp16 in staging), layout (b,h,s,dd)
    qkv_proj<<<dim3(4, 64, 3), 256, 0, stream>>>(query, key, value,
                                                 Wq, Wk, Wv, bq, bk, bv,
                                                 Qh, Kh, Vh);
    // 2) flash attention, writes X (b,s,h,dd) fp16
    flash_attn<<<dim3(32, 16), 256, 0, stream>>>(Qh, Kh, Vh, Xh);
    // 3) output projection -> fp32 d_out
    out_proj<<<dim3(4, 64), 256, 0, stream>>>(Xh, Wo, bo, out);
}

// Round 2
// 269.494 us; speedup vs baseline: 1.3285x; 1.3285x over previous
//
#include <hip/hip_runtime.h>

typedef _Float16 f16;
typedef _Float16 half4 __attribute__((ext_vector_type(4)));
typedef _Float16 half8 __attribute__((ext_vector_type(8)));
typedef float f32x4 __attribute__((ext_vector_type(4)));
typedef float float4v __attribute__((ext_vector_type(4)));

#define LOG2E 1.44269504088896340736f

__device__ __forceinline__ half8 cat8(half4 a, half4 b) {
    half8 r;
    r[0] = a[0]; r[1] = a[1]; r[2] = a[2]; r[3] = a[3];
    r[4] = b[0]; r[5] = b[1]; r[6] = b[2]; r[7] = b[3];
    return r;
}

// 8 transpose-reads: B-fragments for ni=0..3 (two 4-row halves each).
// vaddr is per-lane: Vs_base + lg*1024 + lr*8 ; subtile (kq,ddq) at byte
// (kq*4+ddq)*128. Offsets: ni*128 + half*512 (+4096 for the c=1 32-k block).
#define TR8(baddr, d0,d1,d2,d3,d4,d5,d6,d7)                                   \
  asm volatile("ds_read_b64_tr_b16 %0, %8 offset:0\n\t"                       \
               "ds_read_b64_tr_b16 %1, %8 offset:512\n\t"                     \
               "ds_read_b64_tr_b16 %2, %8 offset:128\n\t"                     \
               "ds_read_b64_tr_b16 %3, %8 offset:640\n\t"                     \
               "ds_read_b64_tr_b16 %4, %8 offset:256\n\t"                     \
               "ds_read_b64_tr_b16 %5, %8 offset:768\n\t"                     \
               "ds_read_b64_tr_b16 %6, %8 offset:384\n\t"                     \
               "ds_read_b64_tr_b16 %7, %8 offset:896"                         \
               : "=v"(d0),"=v"(d1),"=v"(d2),"=v"(d3),                         \
                 "=v"(d4),"=v"(d5),"=v"(d6),"=v"(d7)                          \
               : "v"(baddr) : "memory")

#define LGKM0_FENCE()                                                          \
  do { asm volatile("s_waitcnt lgkmcnt(0)" ::: "memory");                      \
       __builtin_amdgcn_sched_barrier(0); } while (0)

// ---------------------------------------------------------------------------
// QKV projection (unchanged from round 1)
// ---------------------------------------------------------------------------
__global__ __launch_bounds__(256) void qkv_proj(
    const float* __restrict__ Aq, const float* __restrict__ Ak, const float* __restrict__ Av,
    const float* __restrict__ Wq, const float* __restrict__ Wk, const float* __restrict__ Wv,
    const float* __restrict__ bq, const float* __restrict__ bk, const float* __restrict__ bv,
    f16* __restrict__ Qh, f16* __restrict__ Kh, f16* __restrict__ Vh)
{
    const int z = blockIdx.z;
    const float* __restrict__ A    = (z == 0) ? Aq : (z == 1) ? Ak : Av;
    const float* __restrict__ W    = (z == 0) ? Wq : (z == 1) ? Wk : Wv;
    const float* __restrict__ bias = (z == 0) ? bq : (z == 1) ? bk : bv;
    f16* __restrict__ dst          = (z == 0) ? Qh : (z == 1) ? Kh : Vh;

    __shared__ __align__(16) f16 As[128 * 40];
    __shared__ __align__(16) f16 Ws[128 * 40];

    const int t  = threadIdx.x;
    const int m0 = blockIdx.y * 128;
    const int n0 = blockIdx.x * 128;
    const int w = t >> 6, lane = t & 63, lr = lane & 15, lg = lane >> 4;
    const int wr = w >> 1, wc = w & 1;

    f32x4 acc[4][4] = {};

    for (int k0 = 0; k0 < 512; k0 += 32) {
        #pragma unroll
        for (int it = 0; it < 2; ++it) {
            int c = t + it * 256;
            int row  = c >> 2;
            int col8 = (c & 3) * 8;

            const float* ga = A + (size_t)(m0 + row) * 512 + k0 + col8;
            float4v a0 = *(const float4v*)ga;
            float4v a1 = *(const float4v*)(ga + 4);
            half8 ha;
            ha[0] = (f16)a0[0]; ha[1] = (f16)a0[1]; ha[2] = (f16)a0[2]; ha[3] = (f16)a0[3];
            ha[4] = (f16)a1[0]; ha[5] = (f16)a1[1]; ha[6] = (f16)a1[2]; ha[7] = (f16)a1[3];
            *(half8*)&As[row * 40 + col8] = ha;

            const float* gw = W + (size_t)(n0 + row) * 512 + k0 + col8;
            float4v w0 = *(const float4v*)gw;
            float4v w1 = *(const float4v*)(gw + 4);
            half8 hw;
            hw[0] = (f16)w0[0]; hw[1] = (f16)w0[1]; hw[2] = (f16)w0[2]; hw[3] = (f16)w0[3];
            hw[4] = (f16)w1[0]; hw[5] = (f16)w1[1]; hw[6] = (f16)w1[2]; hw[7] = (f16)w1[3];
            *(half8*)&Ws[row * 40 + col8] = hw;
        }
        __syncthreads();

        half8 af[4], bf[4];
        #pragma unroll
        for (int i = 0; i < 4; ++i) {
            af[i] = *(const half8*)&As[(wr * 64 + i * 16 + lr) * 40 + lg * 8];
            bf[i] = *(const half8*)&Ws[(wc * 64 + i * 16 + lr) * 40 + lg * 8];
        }
        #pragma unroll
        for (int mi = 0; mi < 4; ++mi)
            #pragma unroll
            for (int ni = 0; ni < 4; ++ni)
                acc[mi][ni] = __builtin_amdgcn_mfma_f32_16x16x32_f16(af[mi], bf[ni], acc[mi][ni], 0, 0, 0);
        __syncthreads();
    }

    #pragma unroll
    for (int mi = 0; mi < 4; ++mi) {
        #pragma unroll
        for (int ni = 0; ni < 4; ++ni) {
            int col = n0 + wc * 64 + ni * 16 + lr;
            float bv_ = bias[col];
            int h  = col >> 6;
            int dd = col & 63;
            #pragma unroll
            for (int r = 0; r < 4; ++r) {
                int row = m0 + wr * 64 + mi * 16 + lg * 4 + r;
                int b = row >> 12;
                int s = row & 4095;
                dst[(((size_t)(b * 8 + h)) * 4096 + s) * 64 + dd] = (f16)(acc[mi][ni][r] + bv_);
            }
        }
    }
}

// ---------------------------------------------------------------------------
// Flash attention v2: 8 waves x 16 q-rows (BQ=128), BK=64.
//  - async staging: next tile's K/V global loads issued before compute
//  - V in LDS subtiled [kq][ddq][4][16], consumed via ds_read_b64_tr_b16
//  - per-wave P LDS roundtrip without barrier
//  - 2 barriers/tile, setprio around MFMA clusters
// ---------------------------------------------------------------------------
__global__ __launch_bounds__(512, 4) void flash_attn(
    const f16* __restrict__ Qh, const f16* __restrict__ Kh, const f16* __restrict__ Vh,
    f16* __restrict__ Xh)
{
    const int bh  = blockIdx.y;           // 0..15  (b*8 + h)
    const int t = threadIdx.x, w = t >> 6, lane = t & 63, lr = lane & 15, lg = lane >> 4;
    const int q0 = blockIdx.x * 128 + w * 16;

    __shared__ __align__(16) f16 Ks[64 * 72];     // [key][d], stride 72
    __shared__ __align__(16) f16 Vs[64 * 64];     // subtiled [kq][ddq][4][16]
    __shared__ __align__(16) f16 Ps[8 * 16 * 72]; // per-wave P [qrow][key]
    f16* Pw = &Ps[w * 16 * 72];

    const size_t hb = (size_t)bh * (4096 * 64);

    // Q A-fragments: A[row=q0+lr][k = c*32 + lg*8 + j]
    half8 aq0 = *(const half8*)&Qh[hb + (size_t)(q0 + lr) * 64 + lg * 8];
    half8 aq1 = *(const half8*)&Qh[hb + (size_t)(q0 + lr) * 64 + 32 + lg * 8];

    // staging: 512 threads x 8 f16 = one 64x64 tile each for K and V
    const int srow = t >> 3;            // 0..63 (key index)
    const int scol = (t & 7) * 8;       // 0..56 (d index)
    const int vdst = ((srow >> 2) * 4 + (scol >> 4)) * 64 + (srow & 3) * 16 + (scol & 15);

    // per-lane base for transpose reads of Vs
    const unsigned vbase = (unsigned)(size_t)(&Vs[0]) + (unsigned)(lg * 1024 + lr * 8);

    f32x4 o[4] = {};
    float mL[4], l[4];
    #pragma unroll
    for (int r = 0; r < 4; ++r) { mL[r] = -INFINITY; l[r] = 0.0f; }

    // prologue: load tile 0
    half8 kreg = *(const half8*)&Kh[hb + (size_t)srow * 64 + scol];
    half8 vreg = *(const half8*)&Vh[hb + (size_t)srow * 64 + scol];

    for (int kt = 0; kt < 4096; kt += 64) {
        // write staged regs -> LDS
        *(half8*)&Ks[srow * 72 + scol] = kreg;
        *(half8*)&Vs[vdst] = vreg;
        __syncthreads();

        // issue next tile's loads (overlap with compute below)
        int ktn = (kt + 64) & 4095;
        kreg = *(const half8*)&Kh[hb + (size_t)(ktn + srow) * 64 + scol];
        vreg = *(const half8*)&Vh[hb + (size_t)(ktn + srow) * 64 + scol];

        // ---- S = Q K^T : M=16 q-rows, N=64 keys, K=64 ----
        f32x4 sf[4] = {};
        #pragma unroll
        for (int c = 0; c < 2; ++c) {
            half8 bk_[4];
            #pragma unroll
            for (int ni = 0; ni < 4; ++ni)
                bk_[ni] = *(const half8*)&Ks[(ni * 16 + lr) * 72 + c * 32 + lg * 8];
            half8 aqc = c ? aq1 : aq0;
            __builtin_amdgcn_s_setprio(1);
            #pragma unroll
            for (int ni = 0; ni < 4; ++ni)
                sf[ni] = __builtin_amdgcn_mfma_f32_16x16x32_f16(aqc, bk_[ni], sf[ni], 0, 0, 0);
            __builtin_amdgcn_s_setprio(0);
        }

        // ---- online softmax; rows q = lg*4 + r, cols k = ni*16 + lr ----
        #pragma unroll
        for (int r = 0; r < 4; ++r) {
            float vmax = fmaxf(fmaxf(sf[0][r], sf[1][r]), fmaxf(sf[2][r], sf[3][r]));
            #pragma unroll
            for (int m = 1; m < 16; m <<= 1)
                vmax = fmaxf(vmax, __shfl_xor(vmax, m, 64));
            float mnewL = fmaxf(mL[r], vmax * LOG2E);
            float alpha = __builtin_amdgcn_exp2f(mL[r] - mnewL);
            float rs = 0.0f;
            #pragma unroll
            for (int ni = 0; ni < 4; ++ni) {
                float p = __builtin_amdgcn_exp2f(fmaf(sf[ni][r], LOG2E, -mnewL));
                Pw[(lg * 4 + r) * 72 + ni * 16 + lr] = (f16)p;
                rs += p;
            }
            #pragma unroll
            for (int m = 1; m < 16; m <<= 1)
                rs += __shfl_xor(rs, m, 64);
            l[r] = fmaf(l[r], alpha, rs);
            mL[r] = mnewL;
            #pragma unroll
            for (int ni = 0; ni < 4; ++ni)
                o[ni][r] *= alpha;
        }
        // (no barrier: Pw is per-wave; LDS ops from one wave are in-order)

        // ---- O += P @ V ----
        {
            half4 u0,u1,u2,u3,u4,u5,u6,u7;
            // c = 0 (keys 0..31)
            TR8(vbase, u0,u1,u2,u3,u4,u5,u6,u7);
            half8 ap0 = *(const half8*)&Pw[lr * 72 + lg * 8];
            LGKM0_FENCE();
            __builtin_amdgcn_s_setprio(1);
            o[0] = __builtin_amdgcn_mfma_f32_16x16x32_f16(ap0, cat8(u0,u1), o[0], 0, 0, 0);
            o[1] = __builtin_amdgcn_mfma_f32_16x16x32_f16(ap0, cat8(u2,u3), o[1], 0, 0, 0);
            o[2] = __builtin_amdgcn_mfma_f32_16x16x32_f16(ap0, cat8(u4,u5), o[2], 0, 0, 0);
            o[3] = __builtin_amdgcn_mfma_f32_16x16x32_f16(ap0, cat8(u6,u7), o[3], 0, 0, 0);
            __builtin_amdgcn_s_setprio(0);
            // c = 1 (keys 32..63): subtile block at +4096 bytes
            TR8(vbase + 4096u, u0,u1,u2,u3,u4,u5,u6,u7);
            half8 ap1 = *(const half8*)&Pw[lr * 72 + 32 + lg * 8];
            LGKM0_FENCE();
            __builtin_amdgcn_s_setprio(1);
            o[0] = __builtin_amdgcn_mfma_f32_16x16x32_f16(ap1, cat8(u0,u1), o[0], 0, 0, 0);
            o[1] = __builtin_amdgcn_mfma_f32_16x16x32_f16(ap1, cat8(u2,u3), o[1], 0, 0, 0);
            o[2] = __builtin_amdgcn_mfma_f32_16x16x32_f16(ap1, cat8(u4,u5), o[2], 0, 0, 0);
            o[3] = __builtin_amdgcn_mfma_f32_16x16x32_f16(ap1, cat8(u6,u7), o[3], 0, 0, 0);
            __builtin_amdgcn_s_setprio(0);
        }
        __syncthreads();
    }

    // ---- epilogue: O / (l * 8), write (b, s, h, dd) fp16 ----
    const int b = bh >> 3, h = bh & 7;
    #pragma unroll
    for (int r = 0; r < 4; ++r) {
        float inv = 1.0f / (l[r] * 8.0f);
        int q = q0 + lg * 4 + r;
        #pragma unroll
        for (int ni = 0; ni < 4; ++ni) {
            int dd = ni * 16 + lr;
            Xh[((size_t)(b * 4096 + q)) * 512 + h * 64 + dd] = (f16)(o[ni][r] * inv);
        }
    }
}

// ---------------------------------------------------------------------------
// Output projection (unchanged from round 1)
// ---------------------------------------------------------------------------
__global__ __launch_bounds__(256) void out_proj(
    const f16* __restrict__ Xh, const float* __restrict__ Wo, const float* __restrict__ bo,
    float* __restrict__ out)
{
    __shared__ __align__(16) f16 As[128 * 40];
    __shared__ __align__(16) f16 Ws[128 * 40];

    const int t  = threadIdx.x;
    const int m0 = blockIdx.y * 128;
    const int n0 = blockIdx.x * 128;
    const int w = t >> 6, lane = t & 63, lr = lane & 15, lg = lane >> 4;
    const int wr = w >> 1, wc = w & 1;

    f32x4 acc[4][4] = {};

    for (int k0 = 0; k0 < 512; k0 += 32) {
        #pragma unroll
        for (int it = 0; it < 2; ++it) {
            int c = t + it * 256;
            int row  = c >> 2;
            int col8 = (c & 3) * 8;

            *(half8*)&As[row * 40 + col8] =
                *(const half8*)&Xh[(size_t)(m0 + row) * 512 + k0 + col8];

            const float* gw = Wo + (size_t)(n0 + row) * 512 + k0 + col8;
            float4v w0 = *(const float4v*)gw;
            float4v w1 = *(const float4v*)(gw + 4);
            half8 hw;
            hw[0] = (f16)w0[0]; hw[1] = (f16)w0[1]; hw[2] = (f16)w0[2]; hw[3] = (f16)w0[3];
            hw[4] = (f16)w1[0]; hw[5] = (f16)w1[1]; hw[6] = (f16)w1[2]; hw[7] = (f16)w1[3];
            *(half8*)&Ws[row * 40 + col8] = hw;
        }
        __syncthreads();

        half8 af[4], bf[4];
        #pragma unroll
        for (int i = 0; i < 4; ++i) {
            af[i] = *(const half8*)&As[(wr * 64 + i * 16 + lr) * 40 + lg * 8];
            bf[i] = *(const half8*)&Ws[(wc * 64 + i * 16 + lr) * 40 + lg * 8];
        }
        #pragma unroll
        for (int mi = 0; mi < 4; ++mi)
            #pragma unroll
            for (int ni = 0; ni < 4; ++ni)
                acc[mi][ni] = __builtin_amdgcn_mfma_f32_16x16x32_f16(af[mi], bf[ni], acc[mi][ni], 0, 0, 0);
        __syncthreads();
    }

    #pragma unroll
    for (int mi = 0; mi < 4; ++mi) {
        #pragma unroll
        for (int ni = 0; ni < 4; ++ni) {
            int col = n0 + wc * 64 + ni * 16 + lr;
            float bb = bo[col];
            #pragma unroll
            for (int r = 0; r < 4; ++r) {
                int row = m0 + wr * 64 + mi * 16 + lg * 4 + r;
                out[(size_t)row * 512 + col] = acc[mi][ni][r] + bb;
            }
        }
    }
}

// ---------------------------------------------------------------------------
extern "C" void kernel_launch(void* const* d_in, const int* in_sizes, int n_in,
                              void* d_out, int out_size, void* d_ws, size_t ws_size,
                              hipStream_t stream) {
    const float* query = (const float*)d_in[0];
    const float* key   = (const float*)d_in[1];
    const float* value = (const float*)d_in[2];
    const float* Wq    = (const float*)d_in[3];
    const float* bq    = (const float*)d_in[4];
    const float* Wk    = (const float*)d_in[5];
    const float* bk    = (const float*)d_in[6];
    const float* Wv    = (const float*)d_in[7];
    const float* bv    = (const float*)d_in[8];
    const float* Wo    = (const float*)d_in[9];
    const float* bo    = (const float*)d_in[10];
    float* out = (float*)d_out;

    char* ws = (char*)d_ws;
    f16* Qh = (f16*)(ws);
    f16* Kh = (f16*)(ws + 8388608);
    f16* Vh = (f16*)(ws + 16777216);
    f16* Xh = (f16*)(ws + 25165824);

    qkv_proj<<<dim3(4, 64, 3), 256, 0, stream>>>(query, key, value,
                                                 Wq, Wk, Wv, bq, bk, bv,
                                                 Qh, Kh, Vh);
    flash_attn<<<dim3(32, 16), 512, 0, stream>>>(Qh, Kh, Vh, Xh);
    out_proj<<<dim3(4, 64), 256, 0, stream>>>(Xh, Wo, bo, out);
}

// Round 4
// 174.113 us; speedup vs baseline: 2.0562x; 1.5478x over previous
//
#include <hip/hip_runtime.h>

typedef _Float16 f16;
typedef __fp16 fp16x2 __attribute__((ext_vector_type(2)));
typedef _Float16 half4 __attribute__((ext_vector_type(4)));
typedef _Float16 half8 __attribute__((ext_vector_type(8)));
typedef float f32x4 __attribute__((ext_vector_type(4)));
typedef float float4v __attribute__((ext_vector_type(4)));

#define LOG2E 1.44269504088896340736f

__device__ __forceinline__ half8 cat8(half4 a, half4 b) {
    half8 r;
    r[0] = a[0]; r[1] = a[1]; r[2] = a[2]; r[3] = a[3];
    r[4] = b[0]; r[5] = b[1]; r[6] = b[2]; r[7] = b[3];
    return r;
}

union H8 { fp16x2 h2[4]; half8 h8; };

// 8 transpose-reads: pairs (db*128, db*128+512) = A-frag halves for db=0..3.
#define TR8(baddr, d0,d1,d2,d3,d4,d5,d6,d7)                                   \
  asm volatile("ds_read_b64_tr_b16 %0, %8 offset:0\n\t"                       \
               "ds_read_b64_tr_b16 %1, %8 offset:512\n\t"                     \
               "ds_read_b64_tr_b16 %2, %8 offset:128\n\t"                     \
               "ds_read_b64_tr_b16 %3, %8 offset:640\n\t"                     \
               "ds_read_b64_tr_b16 %4, %8 offset:256\n\t"                     \
               "ds_read_b64_tr_b16 %5, %8 offset:768\n\t"                     \
               "ds_read_b64_tr_b16 %6, %8 offset:384\n\t"                     \
               "ds_read_b64_tr_b16 %7, %8 offset:896"                         \
               : "=v"(d0),"=v"(d1),"=v"(d2),"=v"(d3),                         \
                 "=v"(d4),"=v"(d5),"=v"(d6),"=v"(d7)                          \
               : "v"(baddr) : "memory")

#define LGKM0_FENCE()                                                          \
  do { asm volatile("s_waitcnt lgkmcnt(0)" ::: "memory");                      \
       __builtin_amdgcn_sched_barrier(0); } while (0)

// ---------------------------------------------------------------------------
// QKV projection (unchanged)
// ---------------------------------------------------------------------------
__global__ __launch_bounds__(256) void qkv_proj(
    const float* __restrict__ Aq, const float* __restrict__ Ak, const float* __restrict__ Av,
    const float* __restrict__ Wq, const float* __restrict__ Wk, const float* __restrict__ Wv,
    const float* __restrict__ bq, const float* __restrict__ bk, const float* __restrict__ bv,
    f16* __restrict__ Qh, f16* __restrict__ Kh, f16* __restrict__ Vh)
{
    const int z = blockIdx.z;
    const float* __restrict__ A    = (z == 0) ? Aq : (z == 1) ? Ak : Av;
    const float* __restrict__ W    = (z == 0) ? Wq : (z == 1) ? Wk : Wv;
    const float* __restrict__ bias = (z == 0) ? bq : (z == 1) ? bk : bv;
    f16* __restrict__ dst          = (z == 0) ? Qh : (z == 1) ? Kh : Vh;

    __shared__ __align__(16) f16 As[128 * 40];
    __shared__ __align__(16) f16 Ws[128 * 40];

    const int t  = threadIdx.x;
    const int m0 = blockIdx.y * 128;
    const int n0 = blockIdx.x * 128;
    const int w = t >> 6, lane = t & 63, lr = lane & 15, lg = lane >> 4;
    const int wr = w >> 1, wc = w & 1;

    f32x4 acc[4][4] = {};

    for (int k0 = 0; k0 < 512; k0 += 32) {
        #pragma unroll
        for (int it = 0; it < 2; ++it) {
            int c = t + it * 256;
            int row  = c >> 2;
            int col8 = (c & 3) * 8;

            const float* ga = A + (size_t)(m0 + row) * 512 + k0 + col8;
            float4v a0 = *(const float4v*)ga;
            float4v a1 = *(const float4v*)(ga + 4);
            half8 ha;
            ha[0] = (f16)a0[0]; ha[1] = (f16)a0[1]; ha[2] = (f16)a0[2]; ha[3] = (f16)a0[3];
            ha[4] = (f16)a1[0]; ha[5] = (f16)a1[1]; ha[6] = (f16)a1[2]; ha[7] = (f16)a1[3];
            *(half8*)&As[row * 40 + col8] = ha;

            const float* gw = W + (size_t)(n0 + row) * 512 + k0 + col8;
            float4v w0 = *(const float4v*)gw;
            float4v w1 = *(const float4v*)(gw + 4);
            half8 hw;
            hw[0] = (f16)w0[0]; hw[1] = (f16)w0[1]; hw[2] = (f16)w0[2]; hw[3] = (f16)w0[3];
            hw[4] = (f16)w1[0]; hw[5] = (f16)w1[1]; hw[6] = (f16)w1[2]; hw[7] = (f16)w1[3];
            *(half8*)&Ws[row * 40 + col8] = hw;
        }
        __syncthreads();

        half8 af[4], bf[4];
        #pragma unroll
        for (int i = 0; i < 4; ++i) {
            af[i] = *(const half8*)&As[(wr * 64 + i * 16 + lr) * 40 + lg * 8];
            bf[i] = *(const half8*)&Ws[(wc * 64 + i * 16 + lr) * 40 + lg * 8];
        }
        #pragma unroll
        for (int mi = 0; mi < 4; ++mi)
            #pragma unroll
            for (int ni = 0; ni < 4; ++ni)
                acc[mi][ni] = __builtin_amdgcn_mfma_f32_16x16x32_f16(af[mi], bf[ni], acc[mi][ni], 0, 0, 0);
        __syncthreads();
    }

    #pragma unroll
    for (int mi = 0; mi < 4; ++mi) {
        #pragma unroll
        for (int ni = 0; ni < 4; ++ni) {
            int col = n0 + wc * 64 + ni * 16 + lr;
            float bv_ = bias[col];
            int h  = col >> 6;
            int dd = col & 63;
            #pragma unroll
            for (int r = 0; r < 4; ++r) {
                int row = m0 + wr * 64 + mi * 16 + lg * 4 + r;
                int b = row >> 12;
                int s = row & 4095;
                dst[(((size_t)(b * 8 + h)) * 4096 + s) * 64 + dd] = (f16)(acc[mi][ni][r] + bv_);
            }
        }
    }
}

// ---------------------------------------------------------------------------
// Flash attention v3: swapped-operand QK^T and PV; softmax in-register.
// 8 waves x 16 q-rows, BK=64, double-buffered K/V LDS (1 barrier/tile).
// Lane (lr,lg): owns q-row q0+lr; holds S/P for keys {16kb+4lg+ro}.
// PV uses key permutation key(k=lg*8+j) = 32c + 16(j>>2) + 4lg + (j&3),
// applied consistently to P^T packing (lane-local) and V LDS subtiling.
// ---------------------------------------------------------------------------
__global__ __launch_bounds__(512, 4) void flash_attn(
    const f16* __restrict__ Qh, const f16* __restrict__ Kh, const f16* __restrict__ Vh,
    f16* __restrict__ Xh)
{
    const int bh  = blockIdx.y;           // 0..15  (b*8 + h)
    const int t = threadIdx.x, w = t >> 6, lane = t & 63, lr = lane & 15, lg = lane >> 4;
    const int q0 = blockIdx.x * 128 + w * 16;

    __shared__ __align__(16) f16 Ks[2][64 * 72];   // [key][d], stride 72
    __shared__ __align__(16) f16 Vs[2][64 * 64];   // subtiled: chi = lg*16+kb*4+db

    const size_t hb = (size_t)bh * (4096 * 64);

    // Q fragments (B-operand of swapped QK^T): lane holds Q[q0+lr][c*32+lg*8+j]
    half8 aq0 = *(const half8*)&Qh[hb + (size_t)(q0 + lr) * 64 + lg * 8];
    half8 aq1 = *(const half8*)&Qh[hb + (size_t)(q0 + lr) * 64 + 32 + lg * 8];

    // staging: 512 threads x 8 f16 per buffer
    const int srow = t >> 3;            // key index 0..63
    const int scol = (t & 7) * 8;       // d index
    const int kdst = srow * 72 + scol;
    const int vdst = ((((srow >> 2) & 3) * 16) + (srow >> 4) * 4 + (scol >> 4)) * 64
                   + (srow & 3) * 16 + (scol & 15);

    f32x4 o[4] = {};
    float mL = -INFINITY, l = 0.0f;

    half8 kreg = *(const half8*)&Kh[hb + (size_t)srow * 64 + scol];
    half8 vreg = *(const half8*)&Vh[hb + (size_t)srow * 64 + scol];

    for (int kt = 0; kt < 4096; kt += 64) {
        const int bi = (kt >> 6) & 1;
        f16* ks = &Ks[bi][0];
        f16* vs = &Vs[bi][0];

        *(half8*)&ks[kdst] = kreg;
        *(half8*)&vs[vdst] = vreg;
        __syncthreads();

        // prefetch next tile into regs (hides HBM under compute)
        int ktn = (kt + 64) & 4095;
        kreg = *(const half8*)&Kh[hb + (size_t)(ktn + srow) * 64 + scol];
        vreg = *(const half8*)&Vh[hb + (size_t)(ktn + srow) * 64 + scol];

        // ---- S^T = K Q^T : sf[kb][ro] = S[16kb+4lg+ro][q0+lr] ----
        f32x4 sf[4] = {};
        #pragma unroll
        for (int c = 0; c < 2; ++c) {
            half8 kf[4];
            #pragma unroll
            for (int kb = 0; kb < 4; ++kb)
                kf[kb] = *(const half8*)&ks[(kb * 16 + lr) * 72 + c * 32 + lg * 8];
            half8 aqc = c ? aq1 : aq0;
            __builtin_amdgcn_s_setprio(1);
            #pragma unroll
            for (int kb = 0; kb < 4; ++kb)
                sf[kb] = __builtin_amdgcn_mfma_f32_16x16x32_f16(kf[kb], aqc, sf[kb], 0, 0, 0);
            __builtin_amdgcn_s_setprio(0);
        }

        // ---- in-register softmax (row is lane-local; 2 shuffles total) ----
        float vm01 = fmaxf(fmaxf(fmaxf(sf[0][0], sf[0][1]), fmaxf(sf[0][2], sf[0][3])),
                           fmaxf(fmaxf(sf[1][0], sf[1][1]), fmaxf(sf[1][2], sf[1][3])));
        float vm23 = fmaxf(fmaxf(fmaxf(sf[2][0], sf[2][1]), fmaxf(sf[2][2], sf[2][3])),
                           fmaxf(fmaxf(sf[3][0], sf[3][1]), fmaxf(sf[3][2], sf[3][3])));
        float vm = fmaxf(vm01, vm23);
        vm = fmaxf(vm, __shfl_xor(vm, 16, 64));
        vm = fmaxf(vm, __shfl_xor(vm, 32, 64));
        float vmL = vm * LOG2E;

        // defer-max: rescale only when the row max grows by >8 (log2 units)
        if (__any(vmL > mL + 8.0f)) {
            float mn = fmaxf(mL, vmL);
            float al = __builtin_amdgcn_exp2f(mL - mn);
            l *= al;
            #pragma unroll
            for (int db = 0; db < 4; ++db) o[db] *= al;
            mL = mn;
        }

        f32x4 pe[4];
        float rs = 0.0f;
        #pragma unroll
        for (int kb = 0; kb < 4; ++kb) {
            #pragma unroll
            for (int ro = 0; ro < 4; ++ro) {
                float p = __builtin_amdgcn_exp2f(fmaf(sf[kb][ro], LOG2E, -mL));
                pe[kb][ro] = p;
                rs += p;
            }
        }
        rs += __shfl_xor(rs, 16, 64);
        rs += __shfl_xor(rs, 32, 64);
        l += rs;

        // pack P^T B-fragments (lane-local, permuted key order)
        H8 pb0u, pb1u;
        pb0u.h2[0] = __builtin_amdgcn_cvt_pkrtz(pe[0][0], pe[0][1]);
        pb0u.h2[1] = __builtin_amdgcn_cvt_pkrtz(pe[0][2], pe[0][3]);
        pb0u.h2[2] = __builtin_amdgcn_cvt_pkrtz(pe[1][0], pe[1][1]);
        pb0u.h2[3] = __builtin_amdgcn_cvt_pkrtz(pe[1][2], pe[1][3]);
        pb1u.h2[0] = __builtin_amdgcn_cvt_pkrtz(pe[2][0], pe[2][1]);
        pb1u.h2[1] = __builtin_amdgcn_cvt_pkrtz(pe[2][2], pe[2][3]);
        pb1u.h2[2] = __builtin_amdgcn_cvt_pkrtz(pe[3][0], pe[3][1]);
        pb1u.h2[3] = __builtin_amdgcn_cvt_pkrtz(pe[3][2], pe[3][3]);

        // ---- O^T += V^T P^T ----
        const unsigned vb = (unsigned)(size_t)vs + (unsigned)(lg * 2048 + lr * 8);
        {
            half4 u0,u1,u2,u3,u4,u5,u6,u7;
            TR8(vb, u0,u1,u2,u3,u4,u5,u6,u7);
            LGKM0_FENCE();
            __builtin_amdgcn_s_setprio(1);
            o[0] = __builtin_amdgcn_mfma_f32_16x16x32_f16(cat8(u0,u1), pb0u.h8, o[0], 0, 0, 0);
            o[1] = __builtin_amdgcn_mfma_f32_16x16x32_f16(cat8(u2,u3), pb0u.h8, o[1], 0, 0, 0);
            o[2] = __builtin_amdgcn_mfma_f32_16x16x32_f16(cat8(u4,u5), pb0u.h8, o[2], 0, 0, 0);
            o[3] = __builtin_amdgcn_mfma_f32_16x16x32_f16(cat8(u6,u7), pb0u.h8, o[3], 0, 0, 0);
            __builtin_amdgcn_s_setprio(0);
            TR8(vb + 1024u, u0,u1,u2,u3,u4,u5,u6,u7);
            LGKM0_FENCE();
            __builtin_amdgcn_s_setprio(1);
            o[0] = __builtin_amdgcn_mfma_f32_16x16x32_f16(cat8(u0,u1), pb1u.h8, o[0], 0, 0, 0);
            o[1] = __builtin_amdgcn_mfma_f32_16x16x32_f16(cat8(u2,u3), pb1u.h8, o[1], 0, 0, 0);
            o[2] = __builtin_amdgcn_mfma_f32_16x16x32_f16(cat8(u4,u5), pb1u.h8, o[2], 0, 0, 0);
            o[3] = __builtin_amdgcn_mfma_f32_16x16x32_f16(cat8(u6,u7), pb1u.h8, o[3], 0, 0, 0);
            __builtin_amdgcn_s_setprio(0);
        }
    }

    // ---- epilogue: O[q][dd] / (l*8); lane owns q=q0+lr, dd=db*16+lg*4+ro ----
    const int b = bh >> 3, h = bh & 7;
    const float inv = 1.0f / (l * 8.0f);
    const int q = q0 + lr;
    #pragma unroll
    for (int db = 0; db < 4; ++db) {
        half4 hv;
        hv[0] = (f16)(o[db][0] * inv);
        hv[1] = (f16)(o[db][1] * inv);
        hv[2] = (f16)(o[db][2] * inv);
        hv[3] = (f16)(o[db][3] * inv);
        *(half4*)&Xh[((size_t)(b * 4096 + q)) * 512 + h * 64 + db * 16 + lg * 4] = hv;
    }
}

// ---------------------------------------------------------------------------
// Output projection (unchanged)
// ---------------------------------------------------------------------------
__global__ __launch_bounds__(256) void out_proj(
    const f16* __restrict__ Xh, const float* __restrict__ Wo, const float* __restrict__ bo,
    float* __restrict__ out)
{
    __shared__ __align__(16) f16 As[128 * 40];
    __shared__ __align__(16) f16 Ws[128 * 40];

    const int t  = threadIdx.x;
    const int m0 = blockIdx.y * 128;
    const int n0 = blockIdx.x * 128;
    const int w = t >> 6, lane = t & 63, lr = lane & 15, lg = lane >> 4;
    const int wr = w >> 1, wc = w & 1;

    f32x4 acc[4][4] = {};

    for (int k0 = 0; k0 < 512; k0 += 32) {
        #pragma unroll
        for (int it = 0; it < 2; ++it) {
            int c = t + it * 256;
            int row  = c >> 2;
            int col8 = (c & 3) * 8;

            *(half8*)&As[row * 40 + col8] =
                *(const half8*)&Xh[(size_t)(m0 + row) * 512 + k0 + col8];

            const float* gw = Wo + (size_t)(n0 + row) * 512 + k0 + col8;
            float4v w0 = *(const float4v*)gw;
            float4v w1 = *(const float4v*)(gw + 4);
            half8 hw;
            hw[0] = (f16)w0[0]; hw[1] = (f16)w0[1]; hw[2] = (f16)w0[2]; hw[3] = (f16)w0[3];
            hw[4] = (f16)w1[0]; hw[5] = (f16)w1[1]; hw[6] = (f16)w1[2]; hw[7] = (f16)w1[3];
            *(half8*)&Ws[row * 40 + col8] = hw;
        }
        __syncthreads();

        half8 af[4], bf[4];
        #pragma unroll
        for (int i = 0; i < 4; ++i) {
            af[i] = *(const half8*)&As[(wr * 64 + i * 16 + lr) * 40 + lg * 8];
            bf[i] = *(const half8*)&Ws[(wc * 64 + i * 16 + lr) * 40 + lg * 8];
        }
        #pragma unroll
        for (int mi = 0; mi < 4; ++mi)
            #pragma unroll
            for (int ni = 0; ni < 4; ++ni)
                acc[mi][ni] = __builtin_amdgcn_mfma_f32_16x16x32_f16(af[mi], bf[ni], acc[mi][ni], 0, 0, 0);
        __syncthreads();
    }

    #pragma unroll
    for (int mi = 0; mi < 4; ++mi) {
        #pragma unroll
        for (int ni = 0; ni < 4; ++ni) {
            int col = n0 + wc * 64 + ni * 16 + lr;
            float bb = bo[col];
            #pragma unroll
            for (int r = 0; r < 4; ++r) {
                int row = m0 + wr * 64 + mi * 16 + lg * 4 + r;
                out[(size_t)row * 512 + col] = acc[mi][ni][r] + bb;
            }
        }
    }
}

// ---------------------------------------------------------------------------
extern "C" void kernel_launch(void* const* d_in, const int* in_sizes, int n_in,
                              void* d_out, int out_size, void* d_ws, size_t ws_size,
                              hipStream_t stream) {
    const float* query = (const float*)d_in[0];
    const float* key   = (const float*)d_in[1];
    const float* value = (const float*)d_in[2];
    const float* Wq    = (const float*)d_in[3];
    const float* bq    = (const float*)d_in[4];
    const float* Wk    = (const float*)d_in[5];
    const float* bk    = (const float*)d_in[6];
    const float* Wv    = (const float*)d_in[7];
    const float* bv    = (const float*)d_in[8];
    const float* Wo    = (const float*)d_in[9];
    const float* bo    = (const float*)d_in[10];
    float* out = (float*)d_out;

    char* ws = (char*)d_ws;
    f16* Qh = (f16*)(ws);
    f16* Kh = (f16*)(ws + 8388608);
    f16* Vh = (f16*)(ws + 16777216);
    f16* Xh = (f16*)(ws + 25165824);

    qkv_proj<<<dim3(4, 64, 3), 256, 0, stream>>>(query, key, value,
                                                 Wq, Wk, Wv, bq, bk, bv,
                                                 Qh, Kh, Vh);
    flash_attn<<<dim3(32, 16), 512, 0, stream>>>(Qh, Kh, Vh, Xh);
    out_proj<<<dim3(4, 64), 256, 0, stream>>>(Xh, Wo, bo, out);
}

// Round 7
// 166.286 us; speedup vs baseline: 2.1530x; 1.0471x over previous
//
#include <hip/hip_runtime.h>

typedef _Float16 f16;
typedef __fp16 fp16x2 __attribute__((ext_vector_type(2)));
typedef _Float16 half4 __attribute__((ext_vector_type(4)));
typedef _Float16 half8 __attribute__((ext_vector_type(8)));
typedef float f32x4 __attribute__((ext_vector_type(4)));
typedef float float4v __attribute__((ext_vector_type(4)));

#define LOG2E 1.44269504088896340736f

__device__ __forceinline__ half8 cat8(half4 a, half4 b) {
    half8 r;
    r[0] = a[0]; r[1] = a[1]; r[2] = a[2]; r[3] = a[3];
    r[4] = b[0]; r[5] = b[1]; r[6] = b[2]; r[7] = b[3];
    return r;
}

union H8 { fp16x2 h2[4]; half8 h8; };

// 8 transpose-reads: pairs (db*128, db*128+512) = A-frag halves for db=0..3.
// "=&v" early-clobber: outputs must never alias the address input.
#define TR8(baddr, d0,d1,d2,d3,d4,d5,d6,d7)                                   \
  asm volatile("ds_read_b64_tr_b16 %0, %8 offset:0\n\t"                       \
               "ds_read_b64_tr_b16 %1, %8 offset:512\n\t"                     \
               "ds_read_b64_tr_b16 %2, %8 offset:128\n\t"                     \
               "ds_read_b64_tr_b16 %3, %8 offset:640\n\t"                     \
               "ds_read_b64_tr_b16 %4, %8 offset:256\n\t"                     \
               "ds_read_b64_tr_b16 %5, %8 offset:768\n\t"                     \
               "ds_read_b64_tr_b16 %6, %8 offset:384\n\t"                     \
               "ds_read_b64_tr_b16 %7, %8 offset:896"                         \
               : "=&v"(d0),"=&v"(d1),"=&v"(d2),"=&v"(d3),                     \
                 "=&v"(d4),"=&v"(d5),"=&v"(d6),"=&v"(d7)                      \
               : "v"(baddr) : "memory")

#define LGKM0_FENCE()                                                          \
  do { asm volatile("s_waitcnt lgkmcnt(0)" ::: "memory");                      \
       __builtin_amdgcn_sched_barrier(0); } while (0)

// v3's in-register online softmax + P packing, verbatim semantics.
__device__ __forceinline__ void softmax_pack(
    f32x4 sf[4], float& mL, float& l, f32x4 o[4], H8& pb0, H8& pb1)
{
    float vm01 = fmaxf(fmaxf(fmaxf(sf[0][0], sf[0][1]), fmaxf(sf[0][2], sf[0][3])),
                       fmaxf(fmaxf(sf[1][0], sf[1][1]), fmaxf(sf[1][2], sf[1][3])));
    float vm23 = fmaxf(fmaxf(fmaxf(sf[2][0], sf[2][1]), fmaxf(sf[2][2], sf[2][3])),
                       fmaxf(fmaxf(sf[3][0], sf[3][1]), fmaxf(sf[3][2], sf[3][3])));
    float vm = fmaxf(vm01, vm23);
    vm = fmaxf(vm, __shfl_xor(vm, 16, 64));
    vm = fmaxf(vm, __shfl_xor(vm, 32, 64));
    float vmL = vm * LOG2E;

    // defer-max: rescale only when the row max grows by >8 (log2 units)
    if (__any(vmL > mL + 8.0f)) {
        float mn = fmaxf(mL, vmL);
        float al = __builtin_amdgcn_exp2f(mL - mn);
        l *= al;
        #pragma unroll
        for (int db = 0; db < 4; ++db) o[db] *= al;
        mL = mn;
    }

    f32x4 pe[4];
    float rs = 0.0f;
    #pragma unroll
    for (int kb = 0; kb < 4; ++kb) {
        #pragma unroll
        for (int ro = 0; ro < 4; ++ro) {
            float p = __builtin_amdgcn_exp2f(fmaf(sf[kb][ro], LOG2E, -mL));
            pe[kb][ro] = p;
            rs += p;
        }
    }
    rs += __shfl_xor(rs, 16, 64);
    rs += __shfl_xor(rs, 32, 64);
    l += rs;

    pb0.h2[0] = __builtin_amdgcn_cvt_pkrtz(pe[0][0], pe[0][1]);
    pb0.h2[1] = __builtin_amdgcn_cvt_pkrtz(pe[0][2], pe[0][3]);
    pb0.h2[2] = __builtin_amdgcn_cvt_pkrtz(pe[1][0], pe[1][1]);
    pb0.h2[3] = __builtin_amdgcn_cvt_pkrtz(pe[1][2], pe[1][3]);
    pb1.h2[0] = __builtin_amdgcn_cvt_pkrtz(pe[2][0], pe[2][1]);
    pb1.h2[1] = __builtin_amdgcn_cvt_pkrtz(pe[2][2], pe[2][3]);
    pb1.h2[2] = __builtin_amdgcn_cvt_pkrtz(pe[3][0], pe[3][1]);
    pb1.h2[3] = __builtin_amdgcn_cvt_pkrtz(pe[3][2], pe[3][3]);
}

// ---------------------------------------------------------------------------
// QKV projection (unchanged)
// ---------------------------------------------------------------------------
__global__ __launch_bounds__(256) void qkv_proj(
    const float* __restrict__ Aq, const float* __restrict__ Ak, const float* __restrict__ Av,
    const float* __restrict__ Wq, const float* __restrict__ Wk, const float* __restrict__ Wv,
    const float* __restrict__ bq, const float* __restrict__ bk, const float* __restrict__ bv,
    f16* __restrict__ Qh, f16* __restrict__ Kh, f16* __restrict__ Vh)
{
    const int z = blockIdx.z;
    const float* __restrict__ A    = (z == 0) ? Aq : (z == 1) ? Ak : Av;
    const float* __restrict__ W    = (z == 0) ? Wq : (z == 1) ? Wk : Wv;
    const float* __restrict__ bias = (z == 0) ? bq : (z == 1) ? bk : bv;
    f16* __restrict__ dst          = (z == 0) ? Qh : (z == 1) ? Kh : Vh;

    __shared__ __align__(16) f16 As[128 * 40];
    __shared__ __align__(16) f16 Ws[128 * 40];

    const int t  = threadIdx.x;
    const int m0 = blockIdx.y * 128;
    const int n0 = blockIdx.x * 128;
    const int w = t >> 6, lane = t & 63, lr = lane & 15, lg = lane >> 4;
    const int wr = w >> 1, wc = w & 1;

    f32x4 acc[4][4] = {};

    for (int k0 = 0; k0 < 512; k0 += 32) {
        #pragma unroll
        for (int it = 0; it < 2; ++it) {
            int c = t + it * 256;
            int row  = c >> 2;
            int col8 = (c & 3) * 8;

            const float* ga = A + (size_t)(m0 + row) * 512 + k0 + col8;
            float4v a0 = *(const float4v*)ga;
            float4v a1 = *(const float4v*)(ga + 4);
            half8 ha;
            ha[0] = (f16)a0[0]; ha[1] = (f16)a0[1]; ha[2] = (f16)a0[2]; ha[3] = (f16)a0[3];
            ha[4] = (f16)a1[0]; ha[5] = (f16)a1[1]; ha[6] = (f16)a1[2]; ha[7] = (f16)a1[3];
            *(half8*)&As[row * 40 + col8] = ha;

            const float* gw = W + (size_t)(n0 + row) * 512 + k0 + col8;
            float4v w0 = *(const float4v*)gw;
            float4v w1 = *(const float4v*)(gw + 4);
            half8 hw;
            hw[0] = (f16)w0[0]; hw[1] = (f16)w0[1]; hw[2] = (f16)w0[2]; hw[3] = (f16)w0[3];
            hw[4] = (f16)w1[0]; hw[5] = (f16)w1[1]; hw[6] = (f16)w1[2]; hw[7] = (f16)w1[3];
            *(half8*)&Ws[row * 40 + col8] = hw;
        }
        __syncthreads();

        half8 af[4], bf[4];
        #pragma unroll
        for (int i = 0; i < 4; ++i) {
            af[i] = *(const half8*)&As[(wr * 64 + i * 16 + lr) * 40 + lg * 8];
            bf[i] = *(const half8*)&Ws[(wc * 64 + i * 16 + lr) * 40 + lg * 8];
        }
        #pragma unroll
        for (int mi = 0; mi < 4; ++mi)
            #pragma unroll
            for (int ni = 0; ni < 4; ++ni)
                acc[mi][ni] = __builtin_amdgcn_mfma_f32_16x16x32_f16(af[mi], bf[ni], acc[mi][ni], 0, 0, 0);
        __syncthreads();
    }

    #pragma unroll
    for (int mi = 0; mi < 4; ++mi) {
        #pragma unroll
        for (int ni = 0; ni < 4; ++ni) {
            int col = n0 + wc * 64 + ni * 16 + lr;
            float bv_ = bias[col];
            int h  = col >> 6;
            int dd = col & 63;
            #pragma unroll
            for (int r = 0; r < 4; ++r) {
                int row = m0 + wr * 64 + mi * 16 + lg * 4 + r;
                int b = row >> 12;
                int s = row & 4095;
                dst[(((size_t)(b * 8 + h)) * 4096 + s) * 64 + dd] = (f16)(acc[mi][ni][r] + bv_);
            }
        }
    }
}

// ---------------------------------------------------------------------------
// Flash attention v6 = v3 structure (passed @129us), with each wave owning
// TWO 16-row q-groups (rows q0..q0+15 and q0+16..q0+31) that SHARE the kf
// K-fragments and the ua/ub V transpose-read fragments. 512 thr / 8 waves,
// BQ=256 per block, stride-72 K (2-way, free), v3 staging/TR8/fence/barrier
// placement unchanged. Per-q-row LDS ingest is halved vs v3.
// ---------------------------------------------------------------------------
__global__ __launch_bounds__(512, 2) void flash_attn(
    const f16* __restrict__ Qh, const f16* __restrict__ Kh, const f16* __restrict__ Vh,
    f16* __restrict__ Xh)
{
    const int bh  = blockIdx.y;           // 0..15  (b*8 + h)
    const int t = threadIdx.x, w = t >> 6, lane = t & 63, lr = lane & 15, lg = lane >> 4;
    const int q0 = blockIdx.x * 256 + w * 32;

    __shared__ __align__(16) f16 Ks[2][64 * 72];   // [key][d], stride 72
    __shared__ __align__(16) f16 Vs[2][64 * 64];   // subtiled for tr_b16 reads

    const size_t hb = (size_t)bh * (4096 * 64);

    // Q fragments (B-operand of swapped QK^T) for both 16-row groups
    half8 aq00 = *(const half8*)&Qh[hb + (size_t)(q0 + lr) * 64 + lg * 8];
    half8 aq01 = *(const half8*)&Qh[hb + (size_t)(q0 + lr) * 64 + 32 + lg * 8];
    half8 aq10 = *(const half8*)&Qh[hb + (size_t)(q0 + 16 + lr) * 64 + lg * 8];
    half8 aq11 = *(const half8*)&Qh[hb + (size_t)(q0 + 16 + lr) * 64 + 32 + lg * 8];

    // staging: 512 threads x 8 f16 per buffer (v3-identical)
    const int srow = t >> 3;            // key index 0..63
    const int scol = (t & 7) * 8;       // d index
    const int kdst = srow * 72 + scol;
    const int vdst = ((((srow >> 2) & 3) * 16) + (srow >> 4) * 4 + (scol >> 4)) * 64
                   + (srow & 3) * 16 + (scol & 15);

    f32x4 o0[4] = {}, o1[4] = {};
    float mL0 = -INFINITY, l0 = 0.0f, mL1 = -INFINITY, l1 = 0.0f;

    const f16* kbase = Kh + hb + (size_t)srow * 64 + scol;
    const f16* vbase = Vh + hb + (size_t)srow * 64 + scol;

    half8 kreg = *(const half8*)kbase;
    half8 vreg = *(const half8*)vbase;

    for (int kt = 0; kt < 4096; kt += 64) {
        const int bi = (kt >> 6) & 1;
        f16* ks = &Ks[bi][0];
        f16* vs = &Vs[bi][0];

        *(half8*)&ks[kdst] = kreg;
        *(half8*)&vs[vdst] = vreg;
        __syncthreads();

        // prefetch next tile into regs (hides HBM under compute)
        int koff = ((kt + 64) & 4095) << 6;
        kreg = *(const half8*)(kbase + koff);
        vreg = *(const half8*)(vbase + koff);

        // ---- S^T = K Q^T for both q-groups; kf loaded once, used twice ----
        f32x4 sf0[4] = {}, sf1[4] = {};
        #pragma unroll
        for (int c = 0; c < 2; ++c) {
            half8 kf[4];
            #pragma unroll
            for (int kb = 0; kb < 4; ++kb)
                kf[kb] = *(const half8*)&ks[(kb * 16 + lr) * 72 + c * 32 + lg * 8];
            half8 a0 = c ? aq01 : aq00;
            half8 a1 = c ? aq11 : aq10;
            __builtin_amdgcn_s_setprio(1);
            #pragma unroll
            for (int kb = 0; kb < 4; ++kb)
                sf0[kb] = __builtin_amdgcn_mfma_f32_16x16x32_f16(kf[kb], a0, sf0[kb], 0, 0, 0);
            #pragma unroll
            for (int kb = 0; kb < 4; ++kb)
                sf1[kb] = __builtin_amdgcn_mfma_f32_16x16x32_f16(kf[kb], a1, sf1[kb], 0, 0, 0);
            __builtin_amdgcn_s_setprio(0);
        }

        // ---- softmax + P packing, both groups (in-register, v3 semantics)
        H8 p00, p01, p10, p11;
        softmax_pack(sf0, mL0, l0, o0, p00, p01);
        softmax_pack(sf1, mL1, l1, o1, p10, p11);

        // ---- O^T += V^T P^T : TR8 -> fence -> MFMAs (v3 window), V shared
        const unsigned vb = (unsigned)(size_t)vs + (unsigned)(lg * 2048 + lr * 8);
        {
            half4 u0,u1,u2,u3,u4,u5,u6,u7;
            TR8(vb, u0,u1,u2,u3,u4,u5,u6,u7);
            LGKM0_FENCE();
            __builtin_amdgcn_s_setprio(1);
            o0[0] = __builtin_amdgcn_mfma_f32_16x16x32_f16(cat8(u0,u1), p00.h8, o0[0], 0, 0, 0);
            o0[1] = __builtin_amdgcn_mfma_f32_16x16x32_f16(cat8(u2,u3), p00.h8, o0[1], 0, 0, 0);
            o0[2] = __builtin_amdgcn_mfma_f32_16x16x32_f16(cat8(u4,u5), p00.h8, o0[2], 0, 0, 0);
            o0[3] = __builtin_amdgcn_mfma_f32_16x16x32_f16(cat8(u6,u7), p00.h8, o0[3], 0, 0, 0);
            o1[0] = __builtin_amdgcn_mfma_f32_16x16x32_f16(cat8(u0,u1), p10.h8, o1[0], 0, 0, 0);
            o1[1] = __builtin_amdgcn_mfma_f32_16x16x32_f16(cat8(u2,u3), p10.h8, o1[1], 0, 0, 0);
            o1[2] = __builtin_amdgcn_mfma_f32_16x16x32_f16(cat8(u4,u5), p10.h8, o1[2], 0, 0, 0);
            o1[3] = __builtin_amdgcn_mfma_f32_16x16x32_f16(cat8(u6,u7), p10.h8, o1[3], 0, 0, 0);
            __builtin_amdgcn_s_setprio(0);
            TR8(vb + 1024u, u0,u1,u2,u3,u4,u5,u6,u7);
            LGKM0_FENCE();
            __builtin_amdgcn_s_setprio(1);
            o0[0] = __builtin_amdgcn_mfma_f32_16x16x32_f16(cat8(u0,u1), p01.h8, o0[0], 0, 0, 0);
            o0[1] = __builtin_amdgcn_mfma_f32_16x16x32_f16(cat8(u2,u3), p01.h8, o0[1], 0, 0, 0);
            o0[2] = __builtin_amdgcn_mfma_f32_16x16x32_f16(cat8(u4,u5), p01.h8, o0[2], 0, 0, 0);
            o0[3] = __builtin_amdgcn_mfma_f32_16x16x32_f16(cat8(u6,u7), p01.h8, o0[3], 0, 0, 0);
            o1[0] = __builtin_amdgcn_mfma_f32_16x16x32_f16(cat8(u0,u1), p11.h8, o1[0], 0, 0, 0);
            o1[1] = __builtin_amdgcn_mfma_f32_16x16x32_f16(cat8(u2,u3), p11.h8, o1[1], 0, 0, 0);
            o1[2] = __builtin_amdgcn_mfma_f32_16x16x32_f16(cat8(u4,u5), p11.h8, o1[2], 0, 0, 0);
            o1[3] = __builtin_amdgcn_mfma_f32_16x16x32_f16(cat8(u6,u7), p11.h8, o1[3], 0, 0, 0);
            __builtin_amdgcn_s_setprio(0);
        }
    }

    // ---- epilogue: O/(l*8) per group, write (b, s, h, dd) fp16 ----
    const int b = bh >> 3, h = bh & 7;
    const float inv0 = 1.0f / (l0 * 8.0f);
    const float inv1 = 1.0f / (l1 * 8.0f);
    const int q0_ = q0 + lr, q1_ = q0 + 16 + lr;
    #pragma unroll
    for (int db = 0; db < 4; ++db) {
        half4 hv0, hv1;
        hv0[0] = (f16)(o0[db][0] * inv0);
        hv0[1] = (f16)(o0[db][1] * inv0);
        hv0[2] = (f16)(o0[db][2] * inv0);
        hv0[3] = (f16)(o0[db][3] * inv0);
        *(half4*)&Xh[((size_t)(b * 4096 + q0_)) * 512 + h * 64 + db * 16 + lg * 4] = hv0;
        hv1[0] = (f16)(o1[db][0] * inv1);
        hv1[1] = (f16)(o1[db][1] * inv1);
        hv1[2] = (f16)(o1[db][2] * inv1);
        hv1[3] = (f16)(o1[db][3] * inv1);
        *(half4*)&Xh[((size_t)(b * 4096 + q1_)) * 512 + h * 64 + db * 16 + lg * 4] = hv1;
    }
}

// ---------------------------------------------------------------------------
// Output projection (unchanged)
// ---------------------------------------------------------------------------
__global__ __launch_bounds__(256) void out_proj(
    const f16* __restrict__ Xh, const float* __restrict__ Wo, const float* __restrict__ bo,
    float* __restrict__ out)
{
    __shared__ __align__(16) f16 As[128 * 40];
    __shared__ __align__(16) f16 Ws[128 * 40];

    const int t  = threadIdx.x;
    const int m0 = blockIdx.y * 128;
    const int n0 = blockIdx.x * 128;
    const int w = t >> 6, lane = t & 63, lr = lane & 15, lg = lane >> 4;
    const int wr = w >> 1, wc = w & 1;

    f32x4 acc[4][4] = {};

    for (int k0 = 0; k0 < 512; k0 += 32) {
        #pragma unroll
        for (int it = 0; it < 2; ++it) {
            int c = t + it * 256;
            int row  = c >> 2;
            int col8 = (c & 3) * 8;

            *(half8*)&As[row * 40 + col8] =
                *(const half8*)&Xh[(size_t)(m0 + row) * 512 + k0 + col8];

            const float* gw = Wo + (size_t)(n0 + row) * 512 + k0 + col8;
            float4v w0 = *(const float4v*)gw;
            float4v w1 = *(const float4v*)(gw + 4);
            half8 hw;
            hw[0] = (f16)w0[0]; hw[1] = (f16)w0[1]; hw[2] = (f16)w0[2]; hw[3] = (f16)w0[3];
            hw[4] = (f16)w1[0]; hw[5] = (f16)w1[1]; hw[6] = (f16)w1[2]; hw[7] = (f16)w1[3];
            *(half8*)&Ws[row * 40 + col8] = hw;
        }
        __syncthreads();

        half8 af[4], bf[4];
        #pragma unroll
        for (int i = 0; i < 4; ++i) {
            af[i] = *(const half8*)&As[(wr * 64 + i * 16 + lr) * 40 + lg * 8];
            bf[i] = *(const half8*)&Ws[(wc * 64 + i * 16 + lr) * 40 + lg * 8];
        }
        #pragma unroll
        for (int mi = 0; mi < 4; ++mi)
            #pragma unroll
            for (int ni = 0; ni < 4; ++ni)
                acc[mi][ni] = __builtin_amdgcn_mfma_f32_16x16x32_f16(af[mi], bf[ni], acc[mi][ni], 0, 0, 0);
        __syncthreads();
    }

    #pragma unroll
    for (int mi = 0; mi < 4; ++mi) {
        #pragma unroll
        for (int ni = 0; ni < 4; ++ni) {
            int col = n0 + wc * 64 + ni * 16 + lr;
            float bb = bo[col];
            #pragma unroll
            for (int r = 0; r < 4; ++r) {
                int row = m0 + wr * 64 + mi * 16 + lg * 4 + r;
                out[(size_t)row * 512 + col] = acc[mi][ni][r] + bb;
            }
        }
    }
}

// ---------------------------------------------------------------------------
extern "C" void kernel_launch(void* const* d_in, const int* in_sizes, int n_in,
                              void* d_out, int out_size, void* d_ws, size_t ws_size,
                              hipStream_t stream) {
    const float* query = (const float*)d_in[0];
    const float* key   = (const float*)d_in[1];
    const float* value = (const float*)d_in[2];
    const float* Wq    = (const float*)d_in[3];
    const float* bq    = (const float*)d_in[4];
    const float* Wk    = (const float*)d_in[5];
    const float* bk    = (const float*)d_in[6];
    const float* Wv    = (const float*)d_in[7];
    const float* bv    = (const float*)d_in[8];
    const float* Wo    = (const float*)d_in[9];
    const float* bo    = (const float*)d_in[10];
    float* out = (float*)d_out;

    char* ws = (char*)d_ws;
    f16* Qh = (f16*)(ws);
    f16* Kh = (f16*)(ws + 8388608);
    f16* Vh = (f16*)(ws + 16777216);
    f16* Xh = (f16*)(ws + 25165824);

    qkv_proj<<<dim3(4, 64, 3), 256, 0, stream>>>(query, key, value,
                                                 Wq, Wk, Wv, bq, bk, bv,
                                                 Qh, Kh, Vh);
    flash_attn<<<dim3(16, 16), 512, 0, stream>>>(Qh, Kh, Vh, Xh);
    out_proj<<<dim3(4, 64), 256, 0, stream>>>(Xh, Wo, bo, out);
}